// Round 10
// baseline (250.565 us; speedup 1.0000x reference)
//
#include <hip/hip_runtime.h>
#include <hip/hip_fp8.h>

// Problem constants (shapes fixed by the reference setup_inputs()).
#define D 512
#define NTEST 8192
#define NTRAIN 16384
#define BN 128            // block rows (test)
#define BMT 256           // block col-tile (train cols per tile iteration)
#define KB 128            // k elements per LDS stage (R9's KB=256 regressed: conflicts back)
#define NCHUNK 8          // R3/R5-proven: more chunks thrash L2
#define NPART (NCHUNK * 2)          // 2 column-half waves per row per chunk
#define CHUNK_M (NTRAIN / NCHUNK)   // 2048
#define TILES (CHUNK_M / BMT)       // 8
// z = 0.5*512*ln(2*pi) + 512*ln(1.0) + ln(16384)
#define ZCONST 480.20058952863157f

typedef __attribute__((ext_vector_type(4))) int int4v;
typedef __attribute__((ext_vector_type(8))) int int8v;
typedef __attribute__((ext_vector_type(4))) float floatx4;

__device__ __forceinline__ void async_copy16(const void* g, void* l) {
  __builtin_amdgcn_global_load_lds(
      (const __attribute__((address_space(1))) unsigned int*)g,
      (__attribute__((address_space(3))) unsigned int*)l, 16, 0, 0);
}

// Kernel 1: fp32 -> fp8 e4m3 (OCP) in MX-MFMA-friendly permuted layout + fp32
// row squared-norms (from ORIGINAL fp32 -> dot-product quant error unbiased).
// Layout per 128-elem k-block for mfma_scale_f32_16x16x128_f8f6f4: lane quad q
// holds k = q*32 + 0..31; source elem q*32 + h*16 + b -> byte h*64 + q*16 + b.
// (R7 verified: SQ_LDS_BANK_CONFLICT = 0, absmax unchanged.)
__global__ __launch_bounds__(256) void prep_kernel(
    const float* __restrict__ test, const float* __restrict__ train,
    unsigned char* __restrict__ testq, unsigned char* __restrict__ trainq,
    float* __restrict__ x2, float* __restrict__ y2) {
  const int gw = (int)((blockIdx.x * blockDim.x + threadIdx.x) >> 6);
  const int lane = threadIdx.x & 63;
  const float* src;
  unsigned char* dst;
  float* sq;
  if (gw < NTEST) {
    src = test + (size_t)gw * D;
    dst = testq + (size_t)gw * D;
    sq = x2 + gw;
  } else {
    const int r = gw - NTEST;
    src = train + (size_t)r * D;
    dst = trainq + (size_t)r * D;
    sq = y2 + r;
  }
  const int kb = lane >> 4;          // 128-elem k-block
  const int q = (lane >> 2) & 3;     // quad
  const int h = (lane >> 1) & 1;     // k-half within quad's 32
  const int hb = lane & 1;           // 8-byte half of the 16B chunk-half
  const int sbase = kb * 128 + q * 32 + h * 16 + hb * 8;   // source elems
  const int dbase = kb * 128 + h * 64 + q * 16 + hb * 8;   // dest bytes
  float4 v0 = *(const float4*)(src + sbase);
  float4 v1 = *(const float4*)(src + sbase + 4);
  float s = v0.x * v0.x + v0.y * v0.y + v0.z * v0.z + v0.w * v0.w +
            v1.x * v1.x + v1.y * v1.y + v1.z * v1.z + v1.w * v1.w;
  float f[8] = {v0.x, v0.y, v0.z, v0.w, v1.x, v1.y, v1.z, v1.w};
  unsigned long long p = 0;
#pragma unroll
  for (int i = 0; i < 8; ++i) {
    __hip_fp8_e4m3 qv(f[i]);
    p |= (unsigned long long)qv.__x << (8 * i);
  }
  *(unsigned long long*)(dst + dbase) = p;
#pragma unroll
  for (int off = 32; off >= 1; off >>= 1) s += __shfl_xor(s, off);
  if (lane == 0) *sq = s;
}

// Kernel 2: fused MX-fp8 K=128 MFMA GEMM (C = Xtest . Ytrain^T) + online
// logsumexp. R7 structure (two-barrier KB=128 stages, XOR-16B swizzle,
// 0 conflicts) with ONE change: wave tile 64x64 -> 64x128 (waves 2x2 over a
// 128x256 block tile). LDS frag bytes/lane scale with (tile_m + tile_n):
// 256 B -> 384 B per 2x FLOP = 25% less LDS-read traffic (R7's top pipe,
// ~55 us busy). acc 64 -> 128 VGPR; ~230 total fits launch_bounds(256,2)'s
// 256 cap without spilling (R4 lesson: watch WRITE_SIZE).
// R8 lesson: no source-level double-buffering — compiler alias analysis
// turns it into serializing vmcnt(0). R9 lesson: KB=256 reintroduces
// 4 cyc/read bank conflicts; keep the verified KB=128 read formula.
__global__ __launch_bounds__(256, 2) void fused_kernel(
    const unsigned char* __restrict__ A, const unsigned char* __restrict__ B,
    const float* __restrict__ y2, float* __restrict__ part_m,
    float* __restrict__ part_l) {
  __shared__ unsigned char sA[BN * KB];    // 16 KB
  __shared__ unsigned char sB[BMT * KB];   // 32 KB
  const int tid = threadIdx.x;
  const int lane = tid & 63;
  const int w = tid >> 6;
  const int lm = lane & 15;       // row-in-16tile (A) / col-in-16tile (B,C)
  const int lk = lane >> 4;       // quad: k-group / C row quad
  const int rowbase = blockIdx.x * BN;
  const int chunk = blockIdx.y;
  const int wrow = (w >> 1) * 64;    // wave rows: 0 or 64
  const int wcol = (w & 1) * 128;    // wave cols: 0 or 128

  float run_m[16], run_l[16];
#pragma unroll
  for (int i = 0; i < 16; ++i) { run_m[i] = -1e30f; run_l[i] = 0.f; }

  for (int t = 0; t < TILES; ++t) {
    const int colbase = chunk * CHUNK_M + t * BMT;
    float y2v[8];
#pragma unroll
    for (int ct = 0; ct < 8; ++ct)
      y2v[ct] = y2[colbase + wcol + ct * 16 + lm];

    floatx4 acc[4][8];
#pragma unroll
    for (int rt = 0; rt < 4; ++rt)
#pragma unroll
      for (int ct = 0; ct < 8; ++ct)
        acc[rt][ct] = floatx4{0.f, 0.f, 0.f, 0.f};

    for (int kb = 0; kb < D / KB; ++kb) {   // 4 stages of K=128
      const int kbyte = kb * 128;
      __syncthreads();   // protect LDS from readers of previous stage
#pragma unroll
      for (int i = 0; i < 4; ++i) {          // A tile: 16 KB
        const int o = tid * 16 + i * 4096;
        const int r = o >> 7;                // tile row (128 B per row)
        const int csw = (o >> 4) & 7;
        const int off = ((csw ^ (r & 7)) << 4);
        async_copy16(A + (size_t)(rowbase + r) * D + kbyte + off, sA + o);
      }
#pragma unroll
      for (int i = 0; i < 8; ++i) {          // B tile: 32 KB
        const int o = tid * 16 + i * 4096;
        const int r = o >> 7;
        const int csw = (o >> 4) & 7;
        const int off = ((csw ^ (r & 7)) << 4);
        async_copy16(B + (size_t)(colbase + r) * D + kbyte + off, sB + o);
      }
      __syncthreads();   // drain global_load_lds (vmcnt) + publish

      int8v af[4];
#pragma unroll
      for (int rt = 0; rt < 4; ++rt) {
        const int row = wrow + rt * 16 + lm;
        int4v lo = *(const int4v*)&sA[row * KB + ((lk ^ (row & 7)) << 4)];
        int4v hi = *(const int4v*)&sA[row * KB + (((4 + lk) ^ (row & 7)) << 4)];
        af[rt] = __builtin_shufflevector(lo, hi, 0, 1, 2, 3, 4, 5, 6, 7);
      }
#pragma unroll
      for (int ct = 0; ct < 8; ++ct) {       // B frag consumed immediately
        const int row = wcol + ct * 16 + lm;
        int4v lo = *(const int4v*)&sB[row * KB + ((lk ^ (row & 7)) << 4)];
        int4v hi = *(const int4v*)&sB[row * KB + (((4 + lk) ^ (row & 7)) << 4)];
        int8v bfr = __builtin_shufflevector(lo, hi, 0, 1, 2, 3, 4, 5, 6, 7);
#pragma unroll
        for (int rt = 0; rt < 4; ++rt)
          acc[rt][ct] = __builtin_amdgcn_mfma_scale_f32_16x16x128_f8f6f4(
              af[rt], bfr, acc[rt][ct], 0, 0, 0, 127, 0, 127);
      }
    }

    // Epilogue: per-lane online logsumexp update. s = xy - 0.5*y2[col].
    // C layout: col = lane&15, row = (lane>>4)*4 + reg (shape-determined,
    // dtype/FMT-independent — verified m89/m101/m121-m128).
#pragma unroll
    for (int rt = 0; rt < 4; ++rt) {
#pragma unroll
      for (int reg = 0; reg < 4; ++reg) {
        const int idx = rt * 4 + reg;
        float vs[8];
        float tmax = -1e30f;
#pragma unroll
        for (int ct = 0; ct < 8; ++ct) {
          vs[ct] = fmaf(-0.5f, y2v[ct], acc[rt][ct][reg]);
          tmax = fmaxf(tmax, vs[ct]);
        }
        const float nm = fmaxf(run_m[idx], tmax);
        const float alpha = __expf(run_m[idx] - nm);
        float ps = 0.f;
#pragma unroll
        for (int ct = 0; ct < 8; ++ct) ps += __expf(vs[ct] - nm);
        run_l[idx] = fmaf(run_l[idx], alpha, ps);
        run_m[idx] = nm;
      }
    }
  }

  // Merge the 16 lanes (same lk, lm=0..15) sharing each row; write partials.
  // Rows are shared by the two column-half waves (w&1) -> per-(chunk, half)
  // partial slot (the round-1 race fix).
  const int slot = chunk * 2 + (w & 1);
#pragma unroll
  for (int rt = 0; rt < 4; ++rt) {
#pragma unroll
    for (int reg = 0; reg < 4; ++reg) {
      const int idx = rt * 4 + reg;
      float m = run_m[idx], l = run_l[idx];
#pragma unroll
      for (int off = 1; off < 16; off <<= 1) {
        const float om = __shfl_xor(m, off);
        const float ol = __shfl_xor(l, off);
        const float nm2 = fmaxf(m, om);
        l = l * __expf(m - nm2) + ol * __expf(om - nm2);
        m = nm2;
      }
      if (lm == 0) {
        const int grow = rowbase + wrow + rt * 16 + lk * 4 + reg;
        part_m[slot * NTEST + grow] = m;
        part_l[slot * NTEST + grow] = l;
      }
    }
  }
}

// Kernel 3: merge the NPART partial (m,l) pairs per row, add row constant.
__global__ __launch_bounds__(256) void combine_kernel(
    const float* __restrict__ part_m, const float* __restrict__ part_l,
    const float* __restrict__ x2, float* __restrict__ out) {
  const int n = blockIdx.x * blockDim.x + threadIdx.x;
  if (n >= NTEST) return;
  float m[NPART];
  float mx = -1e30f;
#pragma unroll
  for (int c = 0; c < NPART; ++c) {
    m[c] = part_m[c * NTEST + n];
    mx = fmaxf(mx, m[c]);
  }
  float s = 0.f;
#pragma unroll
  for (int c = 0; c < NPART; ++c)
    s += part_l[c * NTEST + n] * __expf(m[c] - mx);
  out[n] = fmaf(-0.5f, x2[n], mx + __logf(s) - ZCONST);
}

extern "C" void kernel_launch(void* const* d_in, const int* in_sizes, int n_in,
                              void* d_out, int out_size, void* d_ws, size_t ws_size,
                              hipStream_t stream) {
  const float* test = (const float*)d_in[0];    // [8192, 512] fp32
  const float* train = (const float*)d_in[1];   // [16384, 512] fp32
  float* out = (float*)d_out;                   // [8192] fp32
  char* ws = (char*)d_ws;

  // Workspace layout (~13.2 MB total):
  unsigned char* testq = (unsigned char*)ws;                         // 4 MB
  unsigned char* trainq = (unsigned char*)(ws + (size_t)NTEST * D);  // 8 MB
  float* x2 = (float*)(ws + (size_t)(NTEST + NTRAIN) * D);           // 32 KB
  float* y2 = x2 + NTEST;                                            // 64 KB
  float* part_m = y2 + NTRAIN;                                       // 512 KB
  float* part_l = part_m + NPART * NTEST;                            // 512 KB

  prep_kernel<<<(NTEST + NTRAIN) / 4, 256, 0, stream>>>(
      test, train, testq, trainq, x2, y2);
  fused_kernel<<<dim3(NTEST / BN, NCHUNK), 256, 0, stream>>>(
      testq, trainq, y2, part_m, part_l);
  combine_kernel<<<NTEST / 256, 256, 0, stream>>>(part_m, part_l, x2, out);
}

// Round 11
// 177.837 us; speedup vs baseline: 1.4090x; 1.4090x over previous
//
#include <hip/hip_runtime.h>
#include <hip/hip_fp8.h>

// Problem constants (shapes fixed by the reference setup_inputs()).
#define D 512
#define NTEST 8192
#define NTRAIN 16384
#define BN 128            // test rows per block
#define BM 128            // train cols per tile
#define KB 128            // k elements per LDS stage (fp8 -> 128 B rows)
#define NCHUNK 8          // R3/R5-proven: more chunks thrash L2
#define NPART (NCHUNK * 2)          // 2 column-half waves per row per chunk
#define CHUNK_M (NTRAIN / NCHUNK)   // 2048
#define TILES (CHUNK_M / BM)        // 16
#define NROWBLK (NTEST / BN)        // 64
// z = 0.5*512*ln(2*pi) + 512*ln(1.0) + ln(16384)
#define ZCONST 480.20058952863157f

typedef __attribute__((ext_vector_type(4))) int int4v;
typedef __attribute__((ext_vector_type(8))) int int8v;
typedef __attribute__((ext_vector_type(4))) float floatx4;

__device__ __forceinline__ void async_copy16(const void* g, void* l) {
  __builtin_amdgcn_global_load_lds(
      (const __attribute__((address_space(1))) unsigned int*)g,
      (__attribute__((address_space(3))) unsigned int*)l, 16, 0, 0);
}

// Kernel 1: fp32 -> fp8 e4m3 (OCP) in MX-MFMA-friendly permuted layout + fp32
// row squared-norms (from ORIGINAL fp32 -> dot-product quant error unbiased).
// Layout per 128-elem k-block for mfma_scale_f32_16x16x128_f8f6f4: lane quad q
// holds k = q*32 + 0..31; source elem q*32 + h*16 + b -> byte h*64 + q*16 + b.
// (R7 verified: SQ_LDS_BANK_CONFLICT = 0, absmax unchanged.)
// Also zeroes the per-rowblock completion counters (ws is re-poisoned 0xAA
// before every launch; stream order guarantees this precedes fused_kernel).
__global__ __launch_bounds__(256) void prep_kernel(
    const float* __restrict__ test, const float* __restrict__ train,
    unsigned char* __restrict__ testq, unsigned char* __restrict__ trainq,
    float* __restrict__ x2, float* __restrict__ y2,
    int* __restrict__ counters) {
  if (blockIdx.x == 0 && threadIdx.x < NROWBLK) counters[threadIdx.x] = 0;
  const int gw = (int)((blockIdx.x * blockDim.x + threadIdx.x) >> 6);
  const int lane = threadIdx.x & 63;
  const float* src;
  unsigned char* dst;
  float* sq;
  if (gw < NTEST) {
    src = test + (size_t)gw * D;
    dst = testq + (size_t)gw * D;
    sq = x2 + gw;
  } else {
    const int r = gw - NTEST;
    src = train + (size_t)r * D;
    dst = trainq + (size_t)r * D;
    sq = y2 + r;
  }
  const int kb = lane >> 4;          // 128-elem k-block
  const int q = (lane >> 2) & 3;     // quad
  const int h = (lane >> 1) & 1;     // k-half within quad's 32
  const int hb = lane & 1;           // 8-byte half of the 16B chunk-half
  const int sbase = kb * 128 + q * 32 + h * 16 + hb * 8;   // source elems
  const int dbase = kb * 128 + h * 64 + q * 16 + hb * 8;   // dest bytes
  float4 v0 = *(const float4*)(src + sbase);
  float4 v1 = *(const float4*)(src + sbase + 4);
  float s = v0.x * v0.x + v0.y * v0.y + v0.z * v0.z + v0.w * v0.w +
            v1.x * v1.x + v1.y * v1.y + v1.z * v1.z + v1.w * v1.w;
  float f[8] = {v0.x, v0.y, v0.z, v0.w, v1.x, v1.y, v1.z, v1.w};
  unsigned long long p = 0;
#pragma unroll
  for (int i = 0; i < 8; ++i) {
    __hip_fp8_e4m3 qv(f[i]);
    p |= (unsigned long long)qv.__x << (8 * i);
  }
  *(unsigned long long*)(dst + dbase) = p;
#pragma unroll
  for (int off = 32; off >= 1; off >>= 1) s += __shfl_xor(s, off);
  if (lane == 0) *sq = s;
}

// Kernel 2: fused MX-fp8 K=128 MFMA GEMM (C = Xtest . Ytrain^T) + online
// logsumexp + split-K-style final combine (last block per rowblock).
// GEMM path is byte-identical to R7 (90 us): two-barrier KB=128 stages,
// XOR-16B swizzle (0 conflicts), 16x16x128 mfma_scale with unit E8M0 scales.
// Graveyard (do not retry): launch_bounds(256,4) -> spill (R4); NCHUNK=16 ->
// L2 thrash (R5); source-level LDS double-buffer -> alias-serialized vmcnt(0)
// (R8); KB=256 -> 4 cyc/read conflicts (R9); 64x128 wave tile -> spill (R10).
__global__ __launch_bounds__(256, 2) void fused_kernel(
    const unsigned char* __restrict__ A, const unsigned char* __restrict__ B,
    const float* __restrict__ y2, const float* __restrict__ x2,
    float* __restrict__ part_m, float* __restrict__ part_l,
    int* __restrict__ counters, float* __restrict__ out) {
  __shared__ unsigned char sA[BN * KB];   // 16 KB
  __shared__ unsigned char sB[BM * KB];   // 16 KB
  __shared__ int done_flag;
  const int tid = threadIdx.x;
  const int lane = tid & 63;
  const int w = tid >> 6;
  const int lm = lane & 15;       // row-in-16tile (A) / col-in-16tile (B,C)
  const int lk = lane >> 4;       // quad: k-group / C row quad
  const int rowbase = blockIdx.x * BN;
  const int chunk = blockIdx.y;
  const int wrow = (w >> 1) * 64;
  const int wcol = (w & 1) * 64;

  float run_m[16], run_l[16];
#pragma unroll
  for (int i = 0; i < 16; ++i) { run_m[i] = -1e30f; run_l[i] = 0.f; }

  for (int t = 0; t < TILES; ++t) {
    const int colbase = chunk * CHUNK_M + t * BM;
    float y2v[4];
#pragma unroll
    for (int ct = 0; ct < 4; ++ct)
      y2v[ct] = y2[colbase + wcol + ct * 16 + lm];

    floatx4 acc[4][4];
#pragma unroll
    for (int rt = 0; rt < 4; ++rt)
#pragma unroll
      for (int ct = 0; ct < 4; ++ct)
        acc[rt][ct] = floatx4{0.f, 0.f, 0.f, 0.f};

    for (int kb = 0; kb < D / KB; ++kb) {   // 4 stages of K=128
      __syncthreads();   // protect LDS from readers of previous stage
#pragma unroll
      for (int i = 0; i < 4; ++i) {
        const int o = tid * 16 + i * 4096;       // dest byte offset (swizzled)
        const int r = o >> 7;                    // tile row (128 B per row)
        const int csw = (o >> 4) & 7;            // swizzled 16B-chunk slot
        const int off = ((csw ^ (r & 7)) << 4);  // byte offset in k-block
        async_copy16(A + (size_t)(rowbase + r) * D + kb * 128 + off, sA + o);
        async_copy16(B + (size_t)(colbase + r) * D + kb * 128 + off, sB + o);
      }
      __syncthreads();   // drain global_load_lds (vmcnt) + publish
      int8v af[4], bfr[4];
#pragma unroll
      for (int rt = 0; rt < 4; ++rt) {
        const int row = wrow + rt * 16 + lm;
        int4v lo = *(const int4v*)&sA[row * KB + ((lk ^ (row & 7)) << 4)];
        int4v hi = *(const int4v*)&sA[row * KB + (((4 + lk) ^ (row & 7)) << 4)];
        af[rt] = __builtin_shufflevector(lo, hi, 0, 1, 2, 3, 4, 5, 6, 7);
      }
#pragma unroll
      for (int ct = 0; ct < 4; ++ct) {
        const int row = wcol + ct * 16 + lm;
        int4v lo = *(const int4v*)&sB[row * KB + ((lk ^ (row & 7)) << 4)];
        int4v hi = *(const int4v*)&sB[row * KB + (((4 + lk) ^ (row & 7)) << 4)];
        bfr[ct] = __builtin_shufflevector(lo, hi, 0, 1, 2, 3, 4, 5, 6, 7);
      }
#pragma unroll
      for (int rt = 0; rt < 4; ++rt)
#pragma unroll
        for (int ct = 0; ct < 4; ++ct)
          acc[rt][ct] = __builtin_amdgcn_mfma_scale_f32_16x16x128_f8f6f4(
              af[rt], bfr[ct], acc[rt][ct], 0, 0, 0, 127, 0, 127);
    }

    // Epilogue: per-lane online logsumexp update. s = xy - 0.5*y2[col].
    // C layout: col = lane&15, row = (lane>>4)*4 + reg (shape-determined,
    // dtype/FMT-independent — verified m89/m101/m121-m128).
#pragma unroll
    for (int rt = 0; rt < 4; ++rt) {
#pragma unroll
      for (int reg = 0; reg < 4; ++reg) {
        const int idx = rt * 4 + reg;
        const float v0 = fmaf(-0.5f, y2v[0], acc[rt][0][reg]);
        const float v1 = fmaf(-0.5f, y2v[1], acc[rt][1][reg]);
        const float v2 = fmaf(-0.5f, y2v[2], acc[rt][2][reg]);
        const float v3 = fmaf(-0.5f, y2v[3], acc[rt][3][reg]);
        const float tmax = fmaxf(fmaxf(v0, v1), fmaxf(v2, v3));
        const float nm = fmaxf(run_m[idx], tmax);
        const float alpha = __expf(run_m[idx] - nm);
        const float ps = __expf(v0 - nm) + __expf(v1 - nm) +
                         __expf(v2 - nm) + __expf(v3 - nm);
        run_l[idx] = fmaf(run_l[idx], alpha, ps);
        run_m[idx] = nm;
      }
    }
  }

  // Merge the 16 lanes (same lk, lm=0..15) sharing each row; write partials.
  // Partial slot is per (chunk, column-half wave) to avoid the round-1 race.
  const int slot = chunk * 2 + (w & 1);
#pragma unroll
  for (int rt = 0; rt < 4; ++rt) {
#pragma unroll
    for (int reg = 0; reg < 4; ++reg) {
      const int idx = rt * 4 + reg;
      float m = run_m[idx], l = run_l[idx];
#pragma unroll
      for (int off = 1; off < 16; off <<= 1) {
        const float om = __shfl_xor(m, off);
        const float ol = __shfl_xor(l, off);
        const float nm2 = fmaxf(m, om);
        l = l * __expf(m - nm2) + ol * __expf(om - nm2);
        m = nm2;
      }
      if (lm == 0) {
        const int grow = rowbase + wrow + rt * 16 + lk * 4 + reg;
        part_m[slot * NTEST + grow] = m;
        part_l[slot * NTEST + grow] = l;
      }
    }
  }

  // Split-K-style completion: last block per rowblock combines the NPART
  // partial (m,l) pairs. Release: threadfence + device-scope atomic (m20).
  __syncthreads();                      // all waves' partial stores issued
  if (tid == 0) {
    __threadfence();                    // publish partials (device scope)
    done_flag = atomicAdd(&counters[blockIdx.x], 1);
  }
  __syncthreads();
  if (done_flag == NCHUNK - 1) {        // we are the last chunk-block
    __threadfence();                    // acquire: see others' partials
    if (tid < BN) {
      const int n = rowbase + tid;
      float mx = -1e30f;
      float pm[NPART];
#pragma unroll
      for (int c = 0; c < NPART; ++c) {
        pm[c] = part_m[c * NTEST + n];
        mx = fmaxf(mx, pm[c]);
      }
      float s = 0.f;
#pragma unroll
      for (int c = 0; c < NPART; ++c)
        s += part_l[c * NTEST + n] * __expf(pm[c] - mx);
      out[n] = fmaf(-0.5f, x2[n], mx + __logf(s) - ZCONST);
    }
  }
}

extern "C" void kernel_launch(void* const* d_in, const int* in_sizes, int n_in,
                              void* d_out, int out_size, void* d_ws, size_t ws_size,
                              hipStream_t stream) {
  const float* test = (const float*)d_in[0];    // [8192, 512] fp32
  const float* train = (const float*)d_in[1];   // [16384, 512] fp32
  float* out = (float*)d_out;                   // [8192] fp32
  char* ws = (char*)d_ws;

  // Workspace layout (~13.2 MB total):
  unsigned char* testq = (unsigned char*)ws;                         // 4 MB
  unsigned char* trainq = (unsigned char*)(ws + (size_t)NTEST * D);  // 8 MB
  float* x2 = (float*)(ws + (size_t)(NTEST + NTRAIN) * D);           // 32 KB
  float* y2 = x2 + NTEST;                                            // 64 KB
  float* part_m = y2 + NTRAIN;                                       // 512 KB
  float* part_l = part_m + NPART * NTEST;                            // 512 KB
  int* counters = (int*)(part_l + NPART * NTEST);                    // 256 B

  prep_kernel<<<(NTEST + NTRAIN) / 4, 256, 0, stream>>>(
      test, train, testq, trainq, x2, y2, counters);
  fused_kernel<<<dim3(NROWBLK, NCHUNK), 256, 0, stream>>>(
      testq, trainq, y2, x2, part_m, part_l, counters, out);
}

// Round 12
// 164.021 us; speedup vs baseline: 1.5276x; 1.0842x over previous
//
#include <hip/hip_runtime.h>
#include <hip/hip_fp8.h>

// Problem constants (shapes fixed by the reference setup_inputs()).
#define D 512
#define NTEST 8192
#define NTRAIN 16384
#define BN 128            // test rows per block
#define BM 128            // train cols per tile
#define KB 128            // k elements per LDS stage (fp8 -> 128 B rows)
#define NCHUNK 8          // R3/R5-proven: more chunks thrash L2
#define NPART (NCHUNK * 2)          // 2 column-half waves per row per chunk
#define CHUNK_M (NTRAIN / NCHUNK)   // 2048
#define TILES (CHUNK_M / BM)        // 16
// z = 0.5*512*ln(2*pi) + 512*ln(1.0) + ln(16384)
#define ZCONST 480.20058952863157f

typedef __attribute__((ext_vector_type(4))) int int4v;
typedef __attribute__((ext_vector_type(8))) int int8v;
typedef __attribute__((ext_vector_type(4))) float floatx4;

__device__ __forceinline__ void async_copy16(const void* g, void* l) {
  __builtin_amdgcn_global_load_lds(
      (const __attribute__((address_space(1))) unsigned int*)g,
      (__attribute__((address_space(3))) unsigned int*)l, 16, 0, 0);
}

// Kernel 1: fp32 -> fp8 e4m3 (OCP) in MX-MFMA-friendly permuted layout + fp32
// row squared-norms (from ORIGINAL fp32 -> dot-product quant error unbiased).
// Layout per 128-elem k-block for mfma_scale_f32_16x16x128_f8f6f4: lane quad q
// holds k = q*32 + 0..31; source elem q*32 + h*16 + b -> byte h*64 + q*16 + b.
// (R7 verified: SQ_LDS_BANK_CONFLICT = 0, absmax unchanged.)
__global__ __launch_bounds__(256) void prep_kernel(
    const float* __restrict__ test, const float* __restrict__ train,
    unsigned char* __restrict__ testq, unsigned char* __restrict__ trainq,
    float* __restrict__ x2, float* __restrict__ y2) {
  const int gw = (int)((blockIdx.x * blockDim.x + threadIdx.x) >> 6);
  const int lane = threadIdx.x & 63;
  const float* src;
  unsigned char* dst;
  float* sq;
  if (gw < NTEST) {
    src = test + (size_t)gw * D;
    dst = testq + (size_t)gw * D;
    sq = x2 + gw;
  } else {
    const int r = gw - NTEST;
    src = train + (size_t)r * D;
    dst = trainq + (size_t)r * D;
    sq = y2 + r;
  }
  const int kb = lane >> 4;          // 128-elem k-block
  const int q = (lane >> 2) & 3;     // quad
  const int h = (lane >> 1) & 1;     // k-half within quad's 32
  const int hb = lane & 1;           // 8-byte half of the 16B chunk-half
  const int sbase = kb * 128 + q * 32 + h * 16 + hb * 8;   // source elems
  const int dbase = kb * 128 + h * 64 + q * 16 + hb * 8;   // dest bytes
  float4 v0 = *(const float4*)(src + sbase);
  float4 v1 = *(const float4*)(src + sbase + 4);
  float s = v0.x * v0.x + v0.y * v0.y + v0.z * v0.z + v0.w * v0.w +
            v1.x * v1.x + v1.y * v1.y + v1.z * v1.z + v1.w * v1.w;
  float f[8] = {v0.x, v0.y, v0.z, v0.w, v1.x, v1.y, v1.z, v1.w};
  unsigned long long p = 0;
#pragma unroll
  for (int i = 0; i < 8; ++i) {
    __hip_fp8_e4m3 qv(f[i]);
    p |= (unsigned long long)qv.__x << (8 * i);
  }
  *(unsigned long long*)(dst + dbase) = p;
#pragma unroll
  for (int off = 32; off >= 1; off >>= 1) s += __shfl_xor(s, off);
  if (lane == 0) *sq = s;
}

// Kernel 2: fused MX-fp8 K=128 MFMA GEMM (C = Xtest . Ytrain^T) + online
// logsumexp. R7 structure (two-barrier stages, XOR-16B swizzle, 0 conflicts,
// 16x16x128 mfma_scale with unit E8M0 scales) with ONE change:
// A-RESIDENT LDS. R7 re-staged the same 64 KB A-tile 16x (once per B-tile).
// gfx950 allows 160 KB LDS per workgroup (rocminfo GROUP pool), so A
// (128 rows x 512 B fp8) stays resident: staged once, per-stage copies drop
// 8 -> 4 per thread, and every per-stage vmcnt drain halves. 80 KB/block =
// exactly 2 blocks/CU (163840).
// Graveyard (do not retry): launch_bounds(256,4) -> spill (R4); NCHUNK=16 ->
// L2 thrash (R5); source-level LDS double-buffer -> alias-serialized vmcnt(0)
// (R8); KB=256 -> 4 cyc/read conflicts (R9); 64x128 wave tile -> spill (R10);
// fused atomic-tail combine -> +16 us in fused (R11).
__global__ __launch_bounds__(256, 2) void fused_kernel(
    const unsigned char* __restrict__ A, const unsigned char* __restrict__ B,
    const float* __restrict__ y2, float* __restrict__ part_m,
    float* __restrict__ part_l) {
  __shared__ unsigned char sA[BN * D];    // 64 KB, full-K A block, resident
  __shared__ unsigned char sB[BM * KB];   // 16 KB, per-stage B tile
  const int tid = threadIdx.x;
  const int lane = tid & 63;
  const int w = tid >> 6;
  const int lm = lane & 15;       // row-in-16tile (A) / col-in-16tile (B,C)
  const int lk = lane >> 4;       // quad: k-group / C row quad
  const int rowbase = blockIdx.x * BN;
  const int chunk = blockIdx.y;
  const int wrow = (w >> 1) * 64;
  const int wcol = (w & 1) * 64;

  // Stage the FULL A block once: 64 KB = 16 x 16 B per thread.
  // Dest row r (512 B/row) holds k-block kb's chunks swizzled per-kb:
  // dest slot csw of (r, kb) holds source chunk csw ^ (r & 7).
#pragma unroll
  for (int i = 0; i < 16; ++i) {
    const int o = tid * 16 + i * 4096;
    const int r = o >> 9;                  // A tile row (512 B per row)
    const int kb = (o >> 7) & 3;           // 128-B k-block within row
    const int csw = (o >> 4) & 7;          // swizzled 16B-chunk slot
    const int off = kb * 128 + ((csw ^ (r & 7)) << 4);
    async_copy16(A + (size_t)(rowbase + r) * D + off, sA + o);
  }

  float run_m[16], run_l[16];
#pragma unroll
  for (int i = 0; i < 16; ++i) { run_m[i] = -1e30f; run_l[i] = 0.f; }

  for (int t = 0; t < TILES; ++t) {
    const int colbase = chunk * CHUNK_M + t * BM;
    float y2v[4];
#pragma unroll
    for (int ct = 0; ct < 4; ++ct)
      y2v[ct] = y2[colbase + wcol + ct * 16 + lm];

    floatx4 acc[4][4];
#pragma unroll
    for (int rt = 0; rt < 4; ++rt)
#pragma unroll
      for (int ct = 0; ct < 4; ++ct)
        acc[rt][ct] = floatx4{0.f, 0.f, 0.f, 0.f};

    for (int kb = 0; kb < D / KB; ++kb) {   // 4 stages of K=128
      __syncthreads();   // protect sB from readers of previous stage
#pragma unroll
      for (int i = 0; i < 4; ++i) {          // B tile only: 16 KB
        const int o = tid * 16 + i * 4096;
        const int r = o >> 7;                // tile row (128 B per row)
        const int csw = (o >> 4) & 7;        // swizzled 16B-chunk slot
        const int off = ((csw ^ (r & 7)) << 4);
        async_copy16(B + (size_t)(colbase + r) * D + kb * 128 + off, sB + o);
      }
      __syncthreads();   // drain global_load_lds (vmcnt) + publish
      int8v af[4], bfr[4];
#pragma unroll
      for (int rt = 0; rt < 4; ++rt) {
        const int row = wrow + rt * 16 + lm;
        const int rb = row * D + kb * 128;
        int4v lo = *(const int4v*)&sA[rb + ((lk ^ (row & 7)) << 4)];
        int4v hi = *(const int4v*)&sA[rb + (((4 + lk) ^ (row & 7)) << 4)];
        af[rt] = __builtin_shufflevector(lo, hi, 0, 1, 2, 3, 4, 5, 6, 7);
      }
#pragma unroll
      for (int ct = 0; ct < 4; ++ct) {
        const int row = wcol + ct * 16 + lm;
        int4v lo = *(const int4v*)&sB[row * KB + ((lk ^ (row & 7)) << 4)];
        int4v hi = *(const int4v*)&sB[row * KB + (((4 + lk) ^ (row & 7)) << 4)];
        bfr[ct] = __builtin_shufflevector(lo, hi, 0, 1, 2, 3, 4, 5, 6, 7);
      }
#pragma unroll
      for (int rt = 0; rt < 4; ++rt)
#pragma unroll
        for (int ct = 0; ct < 4; ++ct)
          acc[rt][ct] = __builtin_amdgcn_mfma_scale_f32_16x16x128_f8f6f4(
              af[rt], bfr[ct], acc[rt][ct], 0, 0, 0, 127, 0, 127);
    }

    // Epilogue: per-lane online logsumexp update. s = xy - 0.5*y2[col].
    // C layout: col = lane&15, row = (lane>>4)*4 + reg (shape-determined,
    // dtype/FMT-independent — verified m89/m101/m121-m128).
#pragma unroll
    for (int rt = 0; rt < 4; ++rt) {
#pragma unroll
      for (int reg = 0; reg < 4; ++reg) {
        const int idx = rt * 4 + reg;
        const float v0 = fmaf(-0.5f, y2v[0], acc[rt][0][reg]);
        const float v1 = fmaf(-0.5f, y2v[1], acc[rt][1][reg]);
        const float v2 = fmaf(-0.5f, y2v[2], acc[rt][2][reg]);
        const float v3 = fmaf(-0.5f, y2v[3], acc[rt][3][reg]);
        const float tmax = fmaxf(fmaxf(v0, v1), fmaxf(v2, v3));
        const float nm = fmaxf(run_m[idx], tmax);
        const float alpha = __expf(run_m[idx] - nm);
        const float ps = __expf(v0 - nm) + __expf(v1 - nm) +
                         __expf(v2 - nm) + __expf(v3 - nm);
        run_l[idx] = fmaf(run_l[idx], alpha, ps);
        run_m[idx] = nm;
      }
    }
  }

  // Merge the 16 lanes (same lk, lm=0..15) sharing each row; write partials.
  // Partial slot is per (chunk, column-half wave) to avoid the round-1 race.
  const int slot = chunk * 2 + (w & 1);
#pragma unroll
  for (int rt = 0; rt < 4; ++rt) {
#pragma unroll
    for (int reg = 0; reg < 4; ++reg) {
      const int idx = rt * 4 + reg;
      float m = run_m[idx], l = run_l[idx];
#pragma unroll
      for (int off = 1; off < 16; off <<= 1) {
        const float om = __shfl_xor(m, off);
        const float ol = __shfl_xor(l, off);
        const float nm2 = fmaxf(m, om);
        l = l * __expf(m - nm2) + ol * __expf(om - nm2);
        m = nm2;
      }
      if (lm == 0) {
        const int grow = rowbase + wrow + rt * 16 + lk * 4 + reg;
        part_m[slot * NTEST + grow] = m;
        part_l[slot * NTEST + grow] = l;
      }
    }
  }
}

// Kernel 3: merge the NPART partial (m,l) pairs per row, add row constant.
__global__ __launch_bounds__(256) void combine_kernel(
    const float* __restrict__ part_m, const float* __restrict__ part_l,
    const float* __restrict__ x2, float* __restrict__ out) {
  const int n = blockIdx.x * blockDim.x + threadIdx.x;
  if (n >= NTEST) return;
  float m[NPART];
  float mx = -1e30f;
#pragma unroll
  for (int c = 0; c < NPART; ++c) {
    m[c] = part_m[c * NTEST + n];
    mx = fmaxf(mx, m[c]);
  }
  float s = 0.f;
#pragma unroll
  for (int c = 0; c < NPART; ++c)
    s += part_l[c * NTEST + n] * __expf(m[c] - mx);
  out[n] = fmaf(-0.5f, x2[n], mx + __logf(s) - ZCONST);
}

extern "C" void kernel_launch(void* const* d_in, const int* in_sizes, int n_in,
                              void* d_out, int out_size, void* d_ws, size_t ws_size,
                              hipStream_t stream) {
  const float* test = (const float*)d_in[0];    // [8192, 512] fp32
  const float* train = (const float*)d_in[1];   // [16384, 512] fp32
  float* out = (float*)d_out;                   // [8192] fp32
  char* ws = (char*)d_ws;

  // Workspace layout (~13.2 MB total):
  unsigned char* testq = (unsigned char*)ws;                         // 4 MB
  unsigned char* trainq = (unsigned char*)(ws + (size_t)NTEST * D);  // 8 MB
  float* x2 = (float*)(ws + (size_t)(NTEST + NTRAIN) * D);           // 32 KB
  float* y2 = x2 + NTEST;                                            // 64 KB
  float* part_m = y2 + NTRAIN;                                       // 512 KB
  float* part_l = part_m + NPART * NTEST;                            // 512 KB

  prep_kernel<<<(NTEST + NTRAIN) / 4, 256, 0, stream>>>(
      test, train, testq, trainq, x2, y2);
  fused_kernel<<<dim3(NTEST / BN, NCHUNK), 256, 0, stream>>>(
      testq, trainq, y2, part_m, part_l);
  combine_kernel<<<NTEST / 256, 256, 0, stream>>>(part_m, part_l, x2, out);
}